// Round 16
// baseline (106.192 us; speedup 1.0000x reference)
//
#include <hip/hip_runtime.h>

// LNNRegression R16: R15 + flat-linear x DMA (2x global_load_lds width-16 per
// 16-step group; no dummy tail) + unpredicated same-value pair writes.
//   role0: x DMA + MFMA gate/y/pre + tau (lag 0)
//   role1: LTC recurrence both cells, in-reg DPP butterfly (lag 2) [setprio]
//   role2: fusion MFMA -> ltcpk ring[2] (lag 3)
//   role3: attention MFMA + static-max softmax (lag 4)

#define T_  512
#define D_  31
#define GR_ 16
#define NG_ 32
#define NIT 36
#define L2E 1.4426950408889634f
#define TS_ 2.8853900817779268f   // 2/ln2, folded into tanh-input weights

typedef decltype(__builtin_amdgcn_cvt_pkrtz(0.0f, 0.0f)) h2;  // <2 x half>
typedef _Float16 h8v __attribute__((ext_vector_type(8)));
typedef float    f4v __attribute__((ext_vector_type(4)));

__device__ __forceinline__ float fexp2(float x){ return __builtin_amdgcn_exp2f(x); }
__device__ __forceinline__ float frcp (float x){ return __builtin_amdgcn_rcpf(x); }
// input pre-scaled by TS_: tanh(x/TS_) = 1 - 2/(1+2^x)
__device__ __forceinline__ float tanh_pre(float x){
    return 1.0f - 2.0f * frcp(1.0f + fexp2(x));
}
__device__ __forceinline__ h2 cvt2(float a, float b){ return __builtin_amdgcn_cvt_pkrtz(a, b); }
__device__ __forceinline__ h2 bch2(unsigned v){ return __builtin_bit_cast(h2, v); }
__device__ __forceinline__ unsigned bcu(h2 v){ return __builtin_bit_cast(unsigned, v); }

template <int CTRL>
__device__ __forceinline__ float dppf(float v){
    int r = __builtin_amdgcn_update_dpp(0, __builtin_bit_cast(int, v),
                                        CTRL, 0xf, 0xf, true);
    return __builtin_bit_cast(float, r);
}
template <int CTRL>
__device__ __forceinline__ unsigned dppu(unsigned v){
    return (unsigned)__builtin_amdgcn_update_dpp(0, (int)v, CTRL, 0xf, 0xf, true);
}
__device__ __forceinline__ unsigned swz16(unsigned v){
    return (unsigned)__builtin_amdgcn_ds_swizzle((int)v, 0x401F);   // lane^16
}
__device__ __forceinline__ float rsum16(float v){
    v += dppf<0xB1>(v); v += dppf<0x4E>(v); v += dppf<0x141>(v); v += dppf<0x140>(v);
    return v;
}

#if __has_builtin(__builtin_amdgcn_fdot2)
#define FDOT2(acc, a, b) (acc) = __builtin_amdgcn_fdot2((a), (b), (acc), false)
#else
#define FDOT2(acc, a, b) (acc) += (float)(a)[0]*(float)(b)[0] + (float)(a)[1]*(float)(b)[1]
#endif

#define MFMA16(A, Bf, Cf) __builtin_amdgcn_mfma_f32_16x16x32_f16((A), (Bf), (Cf), 0, 0, 0)

#define BAR() do { asm volatile("s_waitcnt lgkmcnt(0)" ::: "memory"); \
                   __builtin_amdgcn_s_barrier();                      \
                   asm volatile("" ::: "memory"); } while (0)

__launch_bounds__(256, 4)
__global__ void lnn_mf(
    const float* __restrict__ X,
    const float* __restrict__ fg_w1, const float* __restrict__ fg_b1,
    const float* __restrict__ fg_w2, const float* __restrict__ fg_b2,
    const float* __restrict__ fwin,  const float* __restrict__ fbin,
    const float* __restrict__ fwrec,
    const float* __restrict__ swin,  const float* __restrict__ sbin,
    const float* __restrict__ swrec,
    const float* __restrict__ fu_w,  const float* __restrict__ fu_b,
    const float* __restrict__ at_w1, const float* __restrict__ at_b1,
    const float* __restrict__ at_w2, const float* __restrict__ at_b2,
    const float* __restrict__ d_w1,  const float* __restrict__ d_b1,
    const float* __restrict__ d_w2,  const float* __restrict__ d_b2,
    const float* __restrict__ o_w1,  const float* __restrict__ o_b1,
    const float* __restrict__ o_w2,  const float* __restrict__ o_b2,
    const float* __restrict__ o_w3,  const float* __restrict__ o_b3,
    const float* __restrict__ i_w1,  const float* __restrict__ i_b1,
    const float* __restrict__ i_w2,  const float* __restrict__ i_b2,
    float* __restrict__ out, int B)
{
    const int b    = blockIdx.x;
    const int tx   = threadIdx.x;
    const int wid  = tx >> 6;
    const int lane = tx & 63;
    const int u    = lane & 31;
    const int hb32 = lane & 32;
    const int role = (wid + b) & 3;

    __shared__ __align__(16) float    xfl   [4][512];      // flat x ring (496+pad)
    __shared__ float    pre_sh[4][GR_][65];                // pre_f|pre_s (scaled)
    __shared__ __align__(16) float    rt_sh [4][GR_];      // 1/tau_fast
    __shared__ __align__(16) unsigned hpk_sh[2][GR_][36];  // h packed f16x2
    __shared__ __align__(16) unsigned ltcpk [2][GR_][36];  // ltc packed f16x2
    __shared__ __align__(16) float    pw_sh [GR_];         // softmax weights
    __shared__ float    ctx_sh[64];

    if (tx < 64) xfl[tx >> 4][496 + (tx & 15)] = 0.0f;  // tail pad = 0 (NaN-safe)

    if (role == 0) {
        // ===== role0: x DMA (flat) + MFMA gate/y/pre + y-shift + tau =====
        const int col = lane & 15, kb = lane >> 4;
        h8v wB[8];
        #pragma unroll
        for (int c = 0; c < 8; ++c) {
            float wv[8];
            #pragma unroll
            for (int j = 0; j < 8; ++j) {
                const int k = kb*8 + j;
                float v = 0.0f;
                if (k < 31) {
                    const int uu = 16*(c & 1) + col;
                    if (c < 2)      v = fg_w1[uu*62 + k] + fg_w1[uu*62 + 31 + k];
                    else if (c < 4) v = fg_w1[uu*62 + 31 + k];
                    else if (c < 6) v = fwin[uu*31 + k];
                    else            v = swin[uu*31 + k];
                }
                wv[j] = v * TS_;        // scale-fold; k=31 weight stays 0
            }
            uint4 qq = { bcu(cvt2(wv[0],wv[1])), bcu(cvt2(wv[2],wv[3])),
                         bcu(cvt2(wv[4],wv[5])), bcu(cvt2(wv[6],wv[7])) };
            wB[c] = __builtin_bit_cast(h8v, qq);
        }
        const float b1c[2] = { fg_b1[col] * TS_, fg_b1[16 + col] * TS_ };
        const float pb[4]  = { fbin[col] * TS_, fbin[16+col] * TS_,
                               sbin[col] * TS_, sbin[16+col] * TS_ };
        const float w2n[2] = { fg_w2[col] * (-L2E), fg_w2[16+col] * (-L2E) };
        const float b2n    = fg_b2[0] * (-L2E);
        // flat DMA: group g = 496 contiguous floats at X + b*T*D + g*496
        const unsigned* Xg = (const unsigned*)(X + (size_t)b * T_ * D_);
        float ypv[2] = {0.0f, 0.0f};
        asm volatile("s_waitcnt vmcnt(0)" ::: "memory");

        // prologue: DMA groups 0,1 (2 loads each)
        #pragma unroll
        for (int gg = 0; gg < 2; ++gg) {
            const unsigned* src = Xg + (size_t)gg * 496;
            __builtin_amdgcn_global_load_lds(
                (const __attribute__((address_space(1))) unsigned*)(src + lane*4),
                (__attribute__((address_space(3))) unsigned*)(&xfl[gg][0]),
                16, 0, 0);
            if (lane < 60)
                __builtin_amdgcn_global_load_lds(
                    (const __attribute__((address_space(1))) unsigned*)(src + 256 + lane*4),
                    (__attribute__((address_space(3))) unsigned*)(&xfl[gg][256]),
                    16, 0, 0);
        }

        for (int i = 0; i < NIT; ++i) {
            if (i < 31) { asm volatile("s_waitcnt vmcnt(2)" ::: "memory"); }
            else        { asm volatile("s_waitcnt vmcnt(0)" ::: "memory"); }
            BAR();
            if (i < 30) {   // DMA group i+2 (last real group = 31)
                const int gq = i + 2;
                const unsigned* src = Xg + (size_t)gq * 496;
                __builtin_amdgcn_global_load_lds(
                    (const __attribute__((address_space(1))) unsigned*)(src + lane*4),
                    (__attribute__((address_space(3))) unsigned*)(&xfl[gq & 3][0]),
                    16, 0, 0);
                if (lane < 60)
                    __builtin_amdgcn_global_load_lds(
                        (const __attribute__((address_space(1))) unsigned*)(src + 256 + lane*4),
                        (__attribute__((address_space(3))) unsigned*)(&xfl[gq & 3][256]),
                        16, 0, 0);
            }
            if (i <= NG_-1) {
                const int sG = i & 3;
                const float* xr = &xfl[sG][col*31 + kb*8];
                float x0 = xr[0], x1 = xr[1], x2 = xr[2], x3 = xr[3];
                float x4 = xr[4], x5 = xr[5], x6 = xr[6], x7 = xr[7];
                uint4 aq = { bcu(cvt2(x0,x1)), bcu(cvt2(x2,x3)),
                             bcu(cvt2(x4,x5)), bcu(cvt2(x6,x7)) };
                h8v Af = __builtin_bit_cast(h8v, aq);
                f4v C[8];
                #pragma unroll
                for (int c = 0; c < 8; ++c) {
                    f4v z = {0.f, 0.f, 0.f, 0.f};
                    C[c] = MFMA16(Af, wB[c], z);
                }
                const int tb = kb * 4;          // row = timestep kb*4+r
                float tp[4] = {0.f, 0.f, 0.f, 0.f};
                #pragma unroll
                for (int p = 0; p < 2; ++p) {
                    f4v G = C[p], Y = C[2+p];   // both pre-scaled by TS_
                    if (i == 0) ypv[p] = __shfl(Y[0], col);     // dx_0 = 0
                    float ylast = __shfl(Y[3], 48 + col);       // row15 -> next
                    float yup   = __shfl(Y[3], (lane - 16) & 63);
                    float ysh0  = (kb == 0) ? ypv[p] : yup;
                    float h1v[4];
                    h1v[0] = tanh_pre(G[0] - ysh0 + b1c[p]);
                    h1v[1] = tanh_pre(G[1] - Y[0] + b1c[p]);
                    h1v[2] = tanh_pre(G[2] - Y[1] + b1c[p]);
                    h1v[3] = tanh_pre(G[3] - Y[2] + b1c[p]);
                    ypv[p] = ylast;
                    #pragma unroll
                    for (int r = 0; r < 4; ++r) tp[r] += h1v[r] * w2n[p];
                }
                float4 rtq;
                #pragma unroll
                for (int r = 0; r < 4; ++r) {   // tau per row
                    float s  = rsum16(tp[r]) + b2n;
                    float cs = frcp(1.0f + fexp2(s));
                    ((float*)&rtq)[r] = frcp(10.0f - 9.99f * cs);
                }
                if (col == 0) *(float4*)&rt_sh[sG][tb] = rtq;
                #pragma unroll
                for (int c = 4; c < 8; ++c) {   // pre outputs (scaled)
                    const int uo = (c < 6 ? 0 : 32) + 16*(c & 1) + col;
                    #pragma unroll
                    for (int r = 0; r < 4; ++r)
                        pre_sh[sG][tb + r][uo] = C[c][r] + pb[c-4];
                }
            }
        }
        asm volatile("s_waitcnt vmcnt(0)" ::: "memory");
    } else if (role == 1) {
        // ===== role1: LTC recurrence, both cells, in-register butterfly =====
        const bool slow = (lane >= 32);
        const float* W  = (slow ? swrec : fwrec) + u * 32;
        const int M0[8] = {0,2,7,5,15,13,8,10};
        const int M1[8] = {1,3,6,4,14,12,9,11};
        h2 wr[16];
        #pragma unroll
        for (int j = 0; j < 16; ++j) {
            const int x = (j & 8) ? 16 : 0;
            wr[j] = cvt2(W[u ^ M0[j & 7] ^ x] * TS_, W[u ^ M1[j & 7] ^ x] * TS_);
        }
        float h_st = 0.0f;

        for (int i = 0; i < NIT; ++i) {
            BAR();
            if (i >= 2 && i <= NG_ + 1) {
                const int gR = i - 2;
                const int sR = gR & 3;
                const int sH = gR & 1;
                float preA[GR_], rtA[GR_];
                #pragma unroll
                for (int k = 0; k < GR_; ++k)
                    preA[k] = pre_sh[sR][k][lane];
                const float4* rr = (const float4*)(&rt_sh[sR][0]);  // broadcast
                float4 r0 = rr[0], r1 = rr[1], r2 = rr[2], r3 = rr[3];
                {
                    float tmp[GR_] = { r0.x,r0.y,r0.z,r0.w, r1.x,r1.y,r1.z,r1.w,
                                       r2.x,r2.y,r2.z,r2.w, r3.x,r3.y,r3.z,r3.w };
                    #pragma unroll
                    for (int k = 0; k < GR_; ++k)
                        rtA[k] = slow ? 0.2f : tmp[k];
                }
                __builtin_amdgcn_s_setprio(1);
                #pragma unroll
                for (int k = 0; k < GR_; ++k) {
                    float hn = dppf<0xB1>(h_st);
                    unsigned u0 = bcu(cvt2(h_st, hn));          // (l, l^1)
                    unsigned w0 = swz16(u0);                    // ^16 (1 LDS op)
                    unsigned u1 = dppu<0x4E>(u0);               // ^2
                    unsigned u2 = dppu<0x141>(u0);              // ^7
                    unsigned u3 = dppu<0x141>(u1);              // ^5
                    unsigned u4 = dppu<0x140>(u0);              // ^15
                    unsigned u5 = dppu<0x140>(u1);              // ^13
                    unsigned u6 = dppu<0x140>(u2);              // ^8
                    unsigned u7 = dppu<0x140>(u3);              // ^10
                    unsigned w1 = dppu<0x4E>(w0);
                    unsigned w2 = dppu<0x141>(w0);
                    unsigned w3 = dppu<0x141>(w1);
                    unsigned w4 = dppu<0x140>(w0);
                    unsigned w5 = dppu<0x140>(w1);
                    unsigned w6 = dppu<0x140>(w2);
                    unsigned w7 = dppu<0x140>(w3);
                    float a0 = 0.f, a1 = 0.f, a2 = 0.f, a3 = 0.f;
                    FDOT2(a0, bch2(u0), wr[0]);  FDOT2(a1, bch2(u1), wr[1]);
                    FDOT2(a2, bch2(u2), wr[2]);  FDOT2(a3, bch2(u3), wr[3]);
                    FDOT2(a0, bch2(u4), wr[4]);  FDOT2(a1, bch2(u5), wr[5]);
                    FDOT2(a2, bch2(u6), wr[6]);  FDOT2(a3, bch2(u7), wr[7]);
                    FDOT2(a0, bch2(w0), wr[8]);  FDOT2(a1, bch2(w1), wr[9]);
                    FDOT2(a2, bch2(w2), wr[10]); FDOT2(a3, bch2(w3), wr[11]);
                    FDOT2(a0, bch2(w4), wr[12]); FDOT2(a1, bch2(w5), wr[13]);
                    FDOT2(a2, bch2(w6), wr[14]); FDOT2(a3, bch2(w7), wr[15]);
                    float v   = (a0 + a1) + (a2 + a3);
                    float upd = tanh_pre(v + preA[k]);
                    h_st += (upd - h_st) * rtA[k];
                    // unpredicated pair-write: lanes 2j,2j+1 write same value
                    float hw = dppf<0xB1>(h_st);
                    h2 pk = (lane & 1) ? cvt2(hw, h_st) : cvt2(h_st, hw);
                    hpk_sh[sH][k][lane >> 1] = bcu(pk);
                }
                __builtin_amdgcn_s_setprio(0);
            }
        }
    } else if (role == 2) {
        // ===== role2: fusion via MFMA (lag 3) =====
        const int col = lane & 15, kb = lane >> 4;
        h8v wF[8];                      // [kc*4 + nc]
        #pragma unroll
        for (int kc = 0; kc < 2; ++kc)
            #pragma unroll
            for (int nc = 0; nc < 4; ++nc) {
                float wv[8];
                #pragma unroll
                for (int j = 0; j < 8; ++j)
                    wv[j] = fu_w[(16*nc + col)*64 + 32*kc + 8*kb + j] * TS_;
                uint4 qq = { bcu(cvt2(wv[0],wv[1])), bcu(cvt2(wv[2],wv[3])),
                             bcu(cvt2(wv[4],wv[5])), bcu(cvt2(wv[6],wv[7])) };
                wF[kc*4 + nc] = __builtin_bit_cast(h8v, qq);
            }
        const float fb4[4] = { fu_b[col] * TS_, fu_b[16+col] * TS_,
                               fu_b[32+col] * TS_, fu_b[48+col] * TS_ };

        for (int i = 0; i < NIT; ++i) {
            BAR();
            if (i >= 3 && i <= NG_ + 2) {
                const int gF = i - 3;
                const int sH = gF & 1;
                const unsigned* hrow = &hpk_sh[sH][col][0];
                uint4 a0q = *(const uint4*)(hrow + kb*4);
                uint4 a1q = *(const uint4*)(hrow + kb*4 + 16);
                h8v A0 = __builtin_bit_cast(h8v, a0q);
                h8v A1 = __builtin_bit_cast(h8v, a1q);
                const int tb = kb * 4;
                #pragma unroll
                for (int nc = 0; nc < 4; ++nc) {
                    f4v c4 = {0.f, 0.f, 0.f, 0.f};
                    c4 = MFMA16(A0, wF[nc],     c4);
                    c4 = MFMA16(A1, wF[4 + nc], c4);
                    #pragma unroll
                    for (int r = 0; r < 4; ++r) {
                        float v  = tanh_pre(c4[r] + fb4[nc]);
                        float vn = dppf<0xB1>(v);
                        h2 pk = (col & 1) ? cvt2(vn, v) : cvt2(v, vn);
                        ltcpk[gF & 1][tb + r][(16*nc + col) >> 1] = bcu(pk);
                    }
                }
            }
        }
    } else {
        // ===== role3: attention MFMA + static-max softmax (lag 4) =====
        const int col = lane & 15, kb = lane >> 4;
        h8v wA[4];                      // [kt*2 + nt]
        #pragma unroll
        for (int kt = 0; kt < 2; ++kt)
            #pragma unroll
            for (int nt = 0; nt < 2; ++nt) {
                float wv[8];
                #pragma unroll
                for (int j = 0; j < 8; ++j)
                    wv[j] = at_w1[(nt*16 + col)*64 + kt*32 + 8*kb + j] * TS_;
                uint4 qq = { bcu(cvt2(wv[0],wv[1])), bcu(cvt2(wv[2],wv[3])),
                             bcu(cvt2(wv[4],wv[5])), bcu(cvt2(wv[6],wv[7])) };
                wA[kt*2 + nt] = __builtin_bit_cast(h8v, qq);
            }
        const float ab1v[2] = { at_b1[col] * TS_, at_b1[16 + col] * TS_ };
        const float w2L[2]  = { at_w2[col] * L2E, at_w2[16 + col] * L2E };
        const float ab2L    = at_b2[0] * L2E;
        float s_run = 0.0f, c_run = 0.0f;

        for (int i = 0; i < NIT; ++i) {
            BAR();
            if (i >= 4) {                       // group i-4 (<= NG_-1 automatic)
                const int gA = i - 4;
                const int sl = gA & 1;
                const unsigned* lrow = &ltcpk[sl][col][0];
                uint4 l0q = *(const uint4*)(lrow + kb*4);
                uint4 l1q = *(const uint4*)(lrow + kb*4 + 16);
                h8v L0 = __builtin_bit_cast(h8v, l0q);
                h8v L1 = __builtin_bit_cast(h8v, l1q);
                f4v CA[2];
                #pragma unroll
                for (int nt = 0; nt < 2; ++nt) {
                    f4v c4 = {0.f, 0.f, 0.f, 0.f};
                    c4 = MFMA16(L0, wA[nt],     c4);
                    c4 = MFMA16(L1, wA[2 + nt], c4);
                    CA[nt] = c4;
                }
                float4 pwq;
                #pragma unroll
                for (int r = 0; r < 4; ++r) {
                    float s = tanh_pre(CA[0][r] + ab1v[0]) * w2L[0]
                            + tanh_pre(CA[1][r] + ab1v[1]) * w2L[1];
                    s = rsum16(s);
                    ((float*)&pwq)[r] = fexp2(s + ab2L);
                }
                if (col == 0) *(float4*)&pw_sh[kb*4] = pwq;
                const float4* pwp = (const float4*)&pw_sh[0];   // broadcast
                float4 q0 = pwp[0], q1 = pwp[1], q2 = pwp[2], q3 = pwp[3];
                float pwA[GR_] = { q0.x,q0.y,q0.z,q0.w, q1.x,q1.y,q1.z,q1.w,
                                   q2.x,q2.y,q2.z,q2.w, q3.x,q3.y,q3.z,q3.w };
                #pragma unroll
                for (int t = 0; t < GR_; ++t) {
                    float ltc = (float)((const _Float16*)(&ltcpk[sl][t][0]))[lane];
                    s_run += pwA[t];
                    c_run += pwA[t] * ltc;
                }
            }
        }
        ctx_sh[lane] = c_run * frcp(s_run);
    }

    __syncthreads();

    // =================== heads (by wid) ===================
    if (wid == 0) {
        float r1 = d_b1[lane];
        #pragma unroll
        for (int c = 0; c < 16; ++c) {
            float4 cq = ((const float4*)ctx_sh)[c];
            float4 wq = ((const float4*)(d_w1 + lane*64))[c];
            r1 += wq.x*cq.x + wq.y*cq.y + wq.z*cq.z + wq.w*cq.w;
        }
        r1 = fmaxf(r1, 0.0f);
        #pragma unroll
        for (int kk = 0; kk < 5; ++kk) {
            float v = d_w2[kk*64 + lane] * r1;
            v += __shfl_xor(v, 1);  v += __shfl_xor(v, 2);
            v += __shfl_xor(v, 4);  v += __shfl_xor(v, 8);
            v += __shfl_xor(v, 16); v += __shfl_xor(v, 32);
            if (lane == 0) out[b*5 + kk] = v + d_b2[kk];
        }
    } else if (wid == 1) {
        float r1 = o_b1[lane];
        #pragma unroll
        for (int c = 0; c < 16; ++c) {
            float4 cq = ((const float4*)ctx_sh)[c];
            float4 wq = ((const float4*)(o_w1 + lane*64))[c];
            r1 += wq.x*cq.x + wq.y*cq.y + wq.z*cq.z + wq.w*cq.w;
        }
        r1 = fmaxf(r1, 0.0f);
        float acc = 0.0f;
        #pragma unroll
        for (int j = 0; j < 32; ++j) {
            float rj = __shfl(r1, hb32 + j);
            acc += o_w2[u*64 + hb32 + j] * rj;
        }
        acc += __shfl_xor(acc, 32);
        float r2 = fmaxf(acc + o_b2[u], 0.0f);
        float v  = o_w3[u] * r2;
        v += __shfl_xor(v, 1);  v += __shfl_xor(v, 2);
        v += __shfl_xor(v, 4);  v += __shfl_xor(v, 8);
        v += __shfl_xor(v, 16);
        if (lane == 0) {
            float e = fexp2((v + o_b3[0]) * -L2E);
            out[5*B + b] = frcp(1.0f + e);
        }
    } else if (wid == 2) {
        float acc = 0.0f;
        #pragma unroll
        for (int c = 0; c < 8; ++c) {
            float4 cq = ((const float4*)(ctx_sh + hb32))[c];
            float4 wq = ((const float4*)(i_w1 + u*64 + hb32))[c];
            acc += wq.x*cq.x + wq.y*cq.y + wq.z*cq.z + wq.w*cq.w;
        }
        acc += __shfl_xor(acc, 32);
        float r1 = fmaxf(acc + i_b1[u], 0.0f);
        float v  = i_w2[u] * r1;
        v += __shfl_xor(v, 1);  v += __shfl_xor(v, 2);
        v += __shfl_xor(v, 4);  v += __shfl_xor(v, 8);
        v += __shfl_xor(v, 16);
        if (lane == 0) {
            float e = fexp2((v + i_b2[0]) * -L2E);
            out[6*B + b] = frcp(1.0f + e);
        }
    }
}

extern "C" void kernel_launch(void* const* d_in, const int* in_sizes, int n_in,
                              void* d_out, int out_size, void* d_ws, size_t ws_size,
                              hipStream_t stream) {
    (void)n_in; (void)out_size; (void)d_ws; (void)ws_size;
    const float* X     = (const float*)d_in[0];
    const float* fg_w1 = (const float*)d_in[1];
    const float* fg_b1 = (const float*)d_in[2];
    const float* fg_w2 = (const float*)d_in[3];
    const float* fg_b2 = (const float*)d_in[4];
    const float* fwin  = (const float*)d_in[5];
    const float* fbin  = (const float*)d_in[6];
    const float* fwrec = (const float*)d_in[7];
    const float* swin  = (const float*)d_in[8];
    const float* sbin  = (const float*)d_in[9];
    const float* swrec = (const float*)d_in[10];
    const float* fu_w  = (const float*)d_in[11];
    const float* fu_b  = (const float*)d_in[12];
    const float* at_w1 = (const float*)d_in[13];
    const float* at_b1 = (const float*)d_in[14];
    const float* at_w2 = (const float*)d_in[15];
    const float* at_b2 = (const float*)d_in[16];
    const float* d_w1  = (const float*)d_in[17];
    const float* d_b1  = (const float*)d_in[18];
    const float* d_w2  = (const float*)d_in[19];
    const float* d_b2  = (const float*)d_in[20];
    const float* o_w1  = (const float*)d_in[21];
    const float* o_b1  = (const float*)d_in[22];
    const float* o_w2  = (const float*)d_in[23];
    const float* o_b2  = (const float*)d_in[24];
    const float* o_w3  = (const float*)d_in[25];
    const float* o_b3  = (const float*)d_in[26];
    const float* i_w1  = (const float*)d_in[27];
    const float* i_b1  = (const float*)d_in[28];
    const float* i_w2  = (const float*)d_in[29];
    const float* i_b2  = (const float*)d_in[30];
    float* out = (float*)d_out;

    const int B = in_sizes[0] / (T_ * D_);
    dim3 grid(B), block(256);
    hipLaunchKernelGGL(lnn_mf, grid, block, 0, stream,
        X, fg_w1, fg_b1, fg_w2, fg_b2, fwin, fbin, fwrec, swin, sbin, swrec,
        fu_w, fu_b, at_w1, at_b1, at_w2, at_b2, d_w1, d_b1, d_w2, d_b2,
        o_w1, o_b1, o_w2, o_b2, o_w3, o_b3, i_w1, i_b1, i_w2, i_b2, out, B);
}

// Round 17
// 94.315 us; speedup vs baseline: 1.1259x; 1.1259x over previous
//
#include <hip/hip_runtime.h>

// LNNRegression R17 = R15 exact revert (measured best: 94.5 us).
// R13 schedule (lags 2/3/4, NIT=36, 4-deep pre/rt rings)
// + scale-folded tanh (TS_ in weights; tanh loses its input mul)
// + vectorized rt (float4 write) and pw (float4 write/read) paths.
//   role0: x DMA + MFMA gate/y/pre + tau (lag 0)
//   role1: LTC recurrence both cells, in-reg DPP butterfly (lag 2) [setprio]
//   role2: fusion MFMA -> ltcpk ring[2] (lag 3)
//   role3: attention MFMA + static-max softmax (lag 4)
// R14 lesson: lag-1 compression + [64][20] pre-transpose regress (jitter + 8-way conflict).
// R16 lesson: flat-x (8x b32 reads) + same-addr pair writes regress (LDS op count/conflicts).

#define T_  512
#define D_  31
#define GR_ 16
#define NG_ 32
#define NIT 36
#define L2E 1.4426950408889634f
#define TS_ 2.8853900817779268f   // 2/ln2, folded into tanh-input weights

typedef decltype(__builtin_amdgcn_cvt_pkrtz(0.0f, 0.0f)) h2;  // <2 x half>
typedef _Float16 h8v __attribute__((ext_vector_type(8)));
typedef float    f4v __attribute__((ext_vector_type(4)));

__device__ __forceinline__ float fexp2(float x){ return __builtin_amdgcn_exp2f(x); }
__device__ __forceinline__ float frcp (float x){ return __builtin_amdgcn_rcpf(x); }
// input pre-scaled by TS_: tanh(x/TS_) = 1 - 2/(1+2^x)
__device__ __forceinline__ float tanh_pre(float x){
    return 1.0f - 2.0f * frcp(1.0f + fexp2(x));
}
__device__ __forceinline__ h2 cvt2(float a, float b){ return __builtin_amdgcn_cvt_pkrtz(a, b); }
__device__ __forceinline__ h2 bch2(unsigned v){ return __builtin_bit_cast(h2, v); }
__device__ __forceinline__ unsigned bcu(h2 v){ return __builtin_bit_cast(unsigned, v); }

template <int CTRL>
__device__ __forceinline__ float dppf(float v){
    int r = __builtin_amdgcn_update_dpp(0, __builtin_bit_cast(int, v),
                                        CTRL, 0xf, 0xf, true);
    return __builtin_bit_cast(float, r);
}
template <int CTRL>
__device__ __forceinline__ unsigned dppu(unsigned v){
    return (unsigned)__builtin_amdgcn_update_dpp(0, (int)v, CTRL, 0xf, 0xf, true);
}
__device__ __forceinline__ unsigned swz16(unsigned v){
    return (unsigned)__builtin_amdgcn_ds_swizzle((int)v, 0x401F);   // lane^16
}
__device__ __forceinline__ float rsum16(float v){
    v += dppf<0xB1>(v); v += dppf<0x4E>(v); v += dppf<0x141>(v); v += dppf<0x140>(v);
    return v;
}

#if __has_builtin(__builtin_amdgcn_fdot2)
#define FDOT2(acc, a, b) (acc) = __builtin_amdgcn_fdot2((a), (b), (acc), false)
#else
#define FDOT2(acc, a, b) (acc) += (float)(a)[0]*(float)(b)[0] + (float)(a)[1]*(float)(b)[1]
#endif

#define MFMA16(A, Bf, Cf) __builtin_amdgcn_mfma_f32_16x16x32_f16((A), (Bf), (Cf), 0, 0, 0)

#define BAR() do { asm volatile("s_waitcnt lgkmcnt(0)" ::: "memory"); \
                   __builtin_amdgcn_s_barrier();                      \
                   asm volatile("" ::: "memory"); } while (0)

__launch_bounds__(256, 4)
__global__ void lnn_mf(
    const float* __restrict__ X,
    const float* __restrict__ fg_w1, const float* __restrict__ fg_b1,
    const float* __restrict__ fg_w2, const float* __restrict__ fg_b2,
    const float* __restrict__ fwin,  const float* __restrict__ fbin,
    const float* __restrict__ fwrec,
    const float* __restrict__ swin,  const float* __restrict__ sbin,
    const float* __restrict__ swrec,
    const float* __restrict__ fu_w,  const float* __restrict__ fu_b,
    const float* __restrict__ at_w1, const float* __restrict__ at_b1,
    const float* __restrict__ at_w2, const float* __restrict__ at_b2,
    const float* __restrict__ d_w1,  const float* __restrict__ d_b1,
    const float* __restrict__ d_w2,  const float* __restrict__ d_b2,
    const float* __restrict__ o_w1,  const float* __restrict__ o_b1,
    const float* __restrict__ o_w2,  const float* __restrict__ o_b2,
    const float* __restrict__ o_w3,  const float* __restrict__ o_b3,
    const float* __restrict__ i_w1,  const float* __restrict__ i_b1,
    const float* __restrict__ i_w2,  const float* __restrict__ i_b2,
    float* __restrict__ out, int B)
{
    const int b    = blockIdx.x;
    const int tx   = threadIdx.x;
    const int wid  = tx >> 6;
    const int lane = tx & 63;
    const int u    = lane & 31;
    const int hb32 = lane & 32;
    const int role = (wid + b) & 3;

    __shared__ __align__(16) float    xr_sh [4][GR_][36];  // x ring (31+pad)
    __shared__ float    xdm   [36];                        // dummy DMA dest
    __shared__ float    pre_sh[4][GR_][65];                // pre_f|pre_s (scaled)
    __shared__ __align__(16) float    rt_sh [4][GR_];      // 1/tau_fast
    __shared__ __align__(16) unsigned hpk_sh[2][GR_][36];  // h packed f16x2
    __shared__ __align__(16) unsigned ltcpk [2][GR_][36];  // ltc packed f16x2
    __shared__ __align__(16) float    pw_sh [GR_];         // softmax weights
    __shared__ float    ctx_sh[64];

    if (tx < 64) xr_sh[tx >> 4][tx & 15][31] = 0.0f;    // k=31 pad = 0

    if (role == 0) {
        // ===== role0: x DMA + MFMA gate/y/pre + y-shift + tau (lag 0) =====
        const int col = lane & 15, kb = lane >> 4;
        h8v wB[8];
        #pragma unroll
        for (int c = 0; c < 8; ++c) {
            float wv[8];
            #pragma unroll
            for (int j = 0; j < 8; ++j) {
                const int k = kb*8 + j;
                float v = 0.0f;
                if (k < 31) {
                    const int uu = 16*(c & 1) + col;
                    if (c < 2)      v = fg_w1[uu*62 + k] + fg_w1[uu*62 + 31 + k];
                    else if (c < 4) v = fg_w1[uu*62 + 31 + k];
                    else if (c < 6) v = fwin[uu*31 + k];
                    else            v = swin[uu*31 + k];
                }
                wv[j] = v * TS_;        // scale-fold (gate, y, pre paths)
            }
            uint4 qq = { bcu(cvt2(wv[0],wv[1])), bcu(cvt2(wv[2],wv[3])),
                         bcu(cvt2(wv[4],wv[5])), bcu(cvt2(wv[6],wv[7])) };
            wB[c] = __builtin_bit_cast(h8v, qq);
        }
        const float b1c[2] = { fg_b1[col] * TS_, fg_b1[16 + col] * TS_ };
        const float pb[4]  = { fbin[col] * TS_, fbin[16+col] * TS_,
                               sbin[col] * TS_, sbin[16+col] * TS_ };
        const float w2n[2] = { fg_w2[col] * (-L2E), fg_w2[16+col] * (-L2E) };
        const float b2n    = fg_b2[0] * (-L2E);
        const unsigned* Xu = (const unsigned*)(X + (size_t)b * T_ * D_ + lane);
        float ypv[2] = {0.0f, 0.0f};
        asm volatile("s_waitcnt vmcnt(0)" ::: "memory");

        // prologue: DMA groups 0,1 (32 loads)
        #pragma unroll
        for (int gg = 0; gg < 2; ++gg)
            #pragma unroll
            for (int k = 0; k < GR_; ++k)
                if (lane < 31)
                    __builtin_amdgcn_global_load_lds(
                        (const __attribute__((address_space(1))) unsigned*)(Xu + (size_t)(GR_*gg + k) * 31),
                        (__attribute__((address_space(3))) unsigned*)(&xr_sh[gg][k][0]),
                        4, 0, 0);

        for (int i = 0; i < NIT; ++i) {
            asm volatile("s_waitcnt vmcnt(16)" ::: "memory");  // group i landed
            BAR();
            {   // DMA group i+2 (dummy tail keeps vmcnt uniform)
                const int gq = i + 2;
                #pragma unroll
                for (int k = 0; k < GR_; ++k) {
                    int tl = GR_*gq + k; if (tl > 511) tl = 511;
                    float* dst = (gq <= NG_-1) ? &xr_sh[gq & 3][k][0] : &xdm[0];
                    if (lane < 31)
                        __builtin_amdgcn_global_load_lds(
                            (const __attribute__((address_space(1))) unsigned*)(Xu + (size_t)tl * 31),
                            (__attribute__((address_space(3))) unsigned*)dst,
                            4, 0, 0);
                }
            }
            if (i <= NG_-1) {
                const int sG = i & 3;
                const float* xrow = &xr_sh[sG][col][kb*8];
                float4 xa = *(const float4*)xrow;
                float4 xb = *(const float4*)(xrow + 4);
                uint4 aq = { bcu(cvt2(xa.x,xa.y)), bcu(cvt2(xa.z,xa.w)),
                             bcu(cvt2(xb.x,xb.y)), bcu(cvt2(xb.z,xb.w)) };
                h8v Af = __builtin_bit_cast(h8v, aq);
                f4v C[8];
                #pragma unroll
                for (int c = 0; c < 8; ++c) {
                    f4v z = {0.f, 0.f, 0.f, 0.f};
                    C[c] = MFMA16(Af, wB[c], z);
                }
                const int tb = kb * 4;          // row = timestep kb*4+r
                float tp[4] = {0.f, 0.f, 0.f, 0.f};
                #pragma unroll
                for (int p = 0; p < 2; ++p) {
                    f4v G = C[p], Y = C[2+p];   // both pre-scaled by TS_
                    if (i == 0) ypv[p] = __shfl(Y[0], col);     // dx_0 = 0
                    float ylast = __shfl(Y[3], 48 + col);       // row15 -> next
                    float yup   = __shfl(Y[3], (lane - 16) & 63);
                    float ysh0  = (kb == 0) ? ypv[p] : yup;
                    float h1v[4];
                    h1v[0] = tanh_pre(G[0] - ysh0 + b1c[p]);
                    h1v[1] = tanh_pre(G[1] - Y[0] + b1c[p]);
                    h1v[2] = tanh_pre(G[2] - Y[1] + b1c[p]);
                    h1v[3] = tanh_pre(G[3] - Y[2] + b1c[p]);
                    ypv[p] = ylast;
                    #pragma unroll
                    for (int r = 0; r < 4; ++r) tp[r] += h1v[r] * w2n[p];
                }
                float4 rtq;
                #pragma unroll
                for (int r = 0; r < 4; ++r) {   // tau per row
                    float s  = rsum16(tp[r]) + b2n;
                    float cs = frcp(1.0f + fexp2(s));
                    ((float*)&rtq)[r] = frcp(10.0f - 9.99f * cs);
                }
                if (col == 0) *(float4*)&rt_sh[sG][tb] = rtq;
                #pragma unroll
                for (int c = 4; c < 8; ++c) {   // pre outputs (scaled)
                    const int uo = (c < 6 ? 0 : 32) + 16*(c & 1) + col;
                    #pragma unroll
                    for (int r = 0; r < 4; ++r)
                        pre_sh[sG][tb + r][uo] = C[c][r] + pb[c-4];
                }
            }
        }
        asm volatile("s_waitcnt vmcnt(0)" ::: "memory");
    } else if (role == 1) {
        // ===== role1: LTC recurrence, both cells, in-register butterfly =====
        const bool slow = (lane >= 32);
        const float* W  = (slow ? swrec : fwrec) + u * 32;
        const int M0[8] = {0,2,7,5,15,13,8,10};
        const int M1[8] = {1,3,6,4,14,12,9,11};
        h2 wr[16];
        #pragma unroll
        for (int j = 0; j < 16; ++j) {
            const int x = (j & 8) ? 16 : 0;
            wr[j] = cvt2(W[u ^ M0[j & 7] ^ x] * TS_, W[u ^ M1[j & 7] ^ x] * TS_);
        }
        float h_st = 0.0f;

        for (int i = 0; i < NIT; ++i) {
            BAR();
            if (i >= 2 && i <= NG_ + 1) {
                const int gR = i - 2;
                const int sR = gR & 3;
                const int sH = gR & 1;
                float preA[GR_], rtA[GR_];
                #pragma unroll
                for (int k = 0; k < GR_; ++k)
                    preA[k] = pre_sh[sR][k][lane];
                const float4* rr = (const float4*)(&rt_sh[sR][0]);  // broadcast
                float4 r0 = rr[0], r1 = rr[1], r2 = rr[2], r3 = rr[3];
                {
                    float tmp[GR_] = { r0.x,r0.y,r0.z,r0.w, r1.x,r1.y,r1.z,r1.w,
                                       r2.x,r2.y,r2.z,r2.w, r3.x,r3.y,r3.z,r3.w };
                    #pragma unroll
                    for (int k = 0; k < GR_; ++k)
                        rtA[k] = slow ? 0.2f : tmp[k];
                }
                __builtin_amdgcn_s_setprio(1);
                #pragma unroll
                for (int k = 0; k < GR_; ++k) {
                    float hn = dppf<0xB1>(h_st);
                    unsigned u0 = bcu(cvt2(h_st, hn));          // (l, l^1)
                    unsigned w0 = swz16(u0);                    // ^16 (1 LDS op)
                    unsigned u1 = dppu<0x4E>(u0);               // ^2
                    unsigned u2 = dppu<0x141>(u0);              // ^7
                    unsigned u3 = dppu<0x141>(u1);              // ^5
                    unsigned u4 = dppu<0x140>(u0);              // ^15
                    unsigned u5 = dppu<0x140>(u1);              // ^13
                    unsigned u6 = dppu<0x140>(u2);              // ^8
                    unsigned u7 = dppu<0x140>(u3);              // ^10
                    unsigned w1 = dppu<0x4E>(w0);
                    unsigned w2 = dppu<0x141>(w0);
                    unsigned w3 = dppu<0x141>(w1);
                    unsigned w4 = dppu<0x140>(w0);
                    unsigned w5 = dppu<0x140>(w1);
                    unsigned w6 = dppu<0x140>(w2);
                    unsigned w7 = dppu<0x140>(w3);
                    float a0 = 0.f, a1 = 0.f, a2 = 0.f, a3 = 0.f;
                    FDOT2(a0, bch2(u0), wr[0]);  FDOT2(a1, bch2(u1), wr[1]);
                    FDOT2(a2, bch2(u2), wr[2]);  FDOT2(a3, bch2(u3), wr[3]);
                    FDOT2(a0, bch2(u4), wr[4]);  FDOT2(a1, bch2(u5), wr[5]);
                    FDOT2(a2, bch2(u6), wr[6]);  FDOT2(a3, bch2(u7), wr[7]);
                    FDOT2(a0, bch2(w0), wr[8]);  FDOT2(a1, bch2(w1), wr[9]);
                    FDOT2(a2, bch2(w2), wr[10]); FDOT2(a3, bch2(w3), wr[11]);
                    FDOT2(a0, bch2(w4), wr[12]); FDOT2(a1, bch2(w5), wr[13]);
                    FDOT2(a2, bch2(w6), wr[14]); FDOT2(a3, bch2(w7), wr[15]);
                    float v   = (a0 + a1) + (a2 + a3);
                    float upd = tanh_pre(v + preA[k]);
                    h_st += (upd - h_st) * rtA[k];
                    float hw = dppf<0xB1>(h_st);
                    if (!(lane & 1))
                        hpk_sh[sH][k][lane >> 1] = bcu(cvt2(h_st, hw));
                }
                __builtin_amdgcn_s_setprio(0);
            }
        }
    } else if (role == 2) {
        // ===== role2: fusion via MFMA (lag 3) =====
        const int col = lane & 15, kb = lane >> 4;
        h8v wF[8];                      // [kc*4 + nc]
        #pragma unroll
        for (int kc = 0; kc < 2; ++kc)
            #pragma unroll
            for (int nc = 0; nc < 4; ++nc) {
                float wv[8];
                #pragma unroll
                for (int j = 0; j < 8; ++j)
                    wv[j] = fu_w[(16*nc + col)*64 + 32*kc + 8*kb + j] * TS_;
                uint4 qq = { bcu(cvt2(wv[0],wv[1])), bcu(cvt2(wv[2],wv[3])),
                             bcu(cvt2(wv[4],wv[5])), bcu(cvt2(wv[6],wv[7])) };
                wF[kc*4 + nc] = __builtin_bit_cast(h8v, qq);
            }
        const float fb4[4] = { fu_b[col] * TS_, fu_b[16+col] * TS_,
                               fu_b[32+col] * TS_, fu_b[48+col] * TS_ };

        for (int i = 0; i < NIT; ++i) {
            BAR();
            if (i >= 3 && i <= NG_ + 2) {
                const int gF = i - 3;
                const int sH = gF & 1;
                const unsigned* hrow = &hpk_sh[sH][col][0];
                uint4 a0q = *(const uint4*)(hrow + kb*4);
                uint4 a1q = *(const uint4*)(hrow + kb*4 + 16);
                h8v A0 = __builtin_bit_cast(h8v, a0q);
                h8v A1 = __builtin_bit_cast(h8v, a1q);
                const int tb = kb * 4;
                #pragma unroll
                for (int nc = 0; nc < 4; ++nc) {
                    f4v c4 = {0.f, 0.f, 0.f, 0.f};
                    c4 = MFMA16(A0, wF[nc],     c4);
                    c4 = MFMA16(A1, wF[4 + nc], c4);
                    #pragma unroll
                    for (int r = 0; r < 4; ++r) {
                        float v  = tanh_pre(c4[r] + fb4[nc]);
                        float vn = dppf<0xB1>(v);
                        h2 pk = (col & 1) ? cvt2(vn, v) : cvt2(v, vn);
                        if (!(col & 1))
                            ltcpk[gF & 1][tb + r][(16*nc + col) >> 1] = bcu(pk);
                    }
                }
            }
        }
    } else {
        // ===== role3: attention MFMA + static-max softmax (lag 4) =====
        const int col = lane & 15, kb = lane >> 4;
        h8v wA[4];                      // [kt*2 + nt]
        #pragma unroll
        for (int kt = 0; kt < 2; ++kt)
            #pragma unroll
            for (int nt = 0; nt < 2; ++nt) {
                float wv[8];
                #pragma unroll
                for (int j = 0; j < 8; ++j)
                    wv[j] = at_w1[(nt*16 + col)*64 + kt*32 + 8*kb + j] * TS_;
                uint4 qq = { bcu(cvt2(wv[0],wv[1])), bcu(cvt2(wv[2],wv[3])),
                             bcu(cvt2(wv[4],wv[5])), bcu(cvt2(wv[6],wv[7])) };
                wA[kt*2 + nt] = __builtin_bit_cast(h8v, qq);
            }
        const float ab1v[2] = { at_b1[col] * TS_, at_b1[16 + col] * TS_ };
        const float w2L[2]  = { at_w2[col] * L2E, at_w2[16 + col] * L2E };
        const float ab2L    = at_b2[0] * L2E;
        float s_run = 0.0f, c_run = 0.0f;

        for (int i = 0; i < NIT; ++i) {
            BAR();
            if (i >= 4) {                       // group i-4 (<= NG_-1 automatic)
                const int gA = i - 4;
                const int sl = gA & 1;
                const unsigned* lrow = &ltcpk[sl][col][0];
                uint4 l0q = *(const uint4*)(lrow + kb*4);
                uint4 l1q = *(const uint4*)(lrow + kb*4 + 16);
                h8v L0 = __builtin_bit_cast(h8v, l0q);
                h8v L1 = __builtin_bit_cast(h8v, l1q);
                f4v CA[2];
                #pragma unroll
                for (int nt = 0; nt < 2; ++nt) {
                    f4v c4 = {0.f, 0.f, 0.f, 0.f};
                    c4 = MFMA16(L0, wA[nt],     c4);
                    c4 = MFMA16(L1, wA[2 + nt], c4);
                    CA[nt] = c4;
                }
                float4 pwq;
                #pragma unroll
                for (int r = 0; r < 4; ++r) {
                    float s = tanh_pre(CA[0][r] + ab1v[0]) * w2L[0]
                            + tanh_pre(CA[1][r] + ab1v[1]) * w2L[1];
                    s = rsum16(s);
                    ((float*)&pwq)[r] = fexp2(s + ab2L);
                }
                if (col == 0) *(float4*)&pw_sh[kb*4] = pwq;
                const float4* pwp = (const float4*)&pw_sh[0];   // broadcast
                float4 q0 = pwp[0], q1 = pwp[1], q2 = pwp[2], q3 = pwp[3];
                float pwA[GR_] = { q0.x,q0.y,q0.z,q0.w, q1.x,q1.y,q1.z,q1.w,
                                   q2.x,q2.y,q2.z,q2.w, q3.x,q3.y,q3.z,q3.w };
                #pragma unroll
                for (int t = 0; t < GR_; ++t) {
                    float ltc = (float)((const _Float16*)(&ltcpk[sl][t][0]))[lane];
                    s_run += pwA[t];
                    c_run += pwA[t] * ltc;
                }
            }
        }
        ctx_sh[lane] = c_run * frcp(s_run);
    }

    __syncthreads();

    // =================== heads (by wid) ===================
    if (wid == 0) {
        float r1 = d_b1[lane];
        #pragma unroll
        for (int c = 0; c < 16; ++c) {
            float4 cq = ((const float4*)ctx_sh)[c];
            float4 wq = ((const float4*)(d_w1 + lane*64))[c];
            r1 += wq.x*cq.x + wq.y*cq.y + wq.z*cq.z + wq.w*cq.w;
        }
        r1 = fmaxf(r1, 0.0f);
        #pragma unroll
        for (int kk = 0; kk < 5; ++kk) {
            float v = d_w2[kk*64 + lane] * r1;
            v += __shfl_xor(v, 1);  v += __shfl_xor(v, 2);
            v += __shfl_xor(v, 4);  v += __shfl_xor(v, 8);
            v += __shfl_xor(v, 16); v += __shfl_xor(v, 32);
            if (lane == 0) out[b*5 + kk] = v + d_b2[kk];
        }
    } else if (wid == 1) {
        float r1 = o_b1[lane];
        #pragma unroll
        for (int c = 0; c < 16; ++c) {
            float4 cq = ((const float4*)ctx_sh)[c];
            float4 wq = ((const float4*)(o_w1 + lane*64))[c];
            r1 += wq.x*cq.x + wq.y*cq.y + wq.z*cq.z + wq.w*cq.w;
        }
        r1 = fmaxf(r1, 0.0f);
        float acc = 0.0f;
        #pragma unroll
        for (int j = 0; j < 32; ++j) {
            float rj = __shfl(r1, hb32 + j);
            acc += o_w2[u*64 + hb32 + j] * rj;
        }
        acc += __shfl_xor(acc, 32);
        float r2 = fmaxf(acc + o_b2[u], 0.0f);
        float v  = o_w3[u] * r2;
        v += __shfl_xor(v, 1);  v += __shfl_xor(v, 2);
        v += __shfl_xor(v, 4);  v += __shfl_xor(v, 8);
        v += __shfl_xor(v, 16);
        if (lane == 0) {
            float e = fexp2((v + o_b3[0]) * -L2E);
            out[5*B + b] = frcp(1.0f + e);
        }
    } else if (wid == 2) {
        float acc = 0.0f;
        #pragma unroll
        for (int c = 0; c < 8; ++c) {
            float4 cq = ((const float4*)(ctx_sh + hb32))[c];
            float4 wq = ((const float4*)(i_w1 + u*64 + hb32))[c];
            acc += wq.x*cq.x + wq.y*cq.y + wq.z*cq.z + wq.w*cq.w;
        }
        acc += __shfl_xor(acc, 32);
        float r1 = fmaxf(acc + i_b1[u], 0.0f);
        float v  = i_w2[u] * r1;
        v += __shfl_xor(v, 1);  v += __shfl_xor(v, 2);
        v += __shfl_xor(v, 4);  v += __shfl_xor(v, 8);
        v += __shfl_xor(v, 16);
        if (lane == 0) {
            float e = fexp2((v + i_b2[0]) * -L2E);
            out[6*B + b] = frcp(1.0f + e);
        }
    }
}

extern "C" void kernel_launch(void* const* d_in, const int* in_sizes, int n_in,
                              void* d_out, int out_size, void* d_ws, size_t ws_size,
                              hipStream_t stream) {
    (void)n_in; (void)out_size; (void)d_ws; (void)ws_size;
    const float* X     = (const float*)d_in[0];
    const float* fg_w1 = (const float*)d_in[1];
    const float* fg_b1 = (const float*)d_in[2];
    const float* fg_w2 = (const float*)d_in[3];
    const float* fg_b2 = (const float*)d_in[4];
    const float* fwin  = (const float*)d_in[5];
    const float* fbin  = (const float*)d_in[6];
    const float* fwrec = (const float*)d_in[7];
    const float* swin  = (const float*)d_in[8];
    const float* sbin  = (const float*)d_in[9];
    const float* swrec = (const float*)d_in[10];
    const float* fu_w  = (const float*)d_in[11];
    const float* fu_b  = (const float*)d_in[12];
    const float* at_w1 = (const float*)d_in[13];
    const float* at_b1 = (const float*)d_in[14];
    const float* at_w2 = (const float*)d_in[15];
    const float* at_b2 = (const float*)d_in[16];
    const float* d_w1  = (const float*)d_in[17];
    const float* d_b1  = (const float*)d_in[18];
    const float* d_w2  = (const float*)d_in[19];
    const float* d_b2  = (const float*)d_in[20];
    const float* o_w1  = (const float*)d_in[21];
    const float* o_b1  = (const float*)d_in[22];
    const float* o_w2  = (const float*)d_in[23];
    const float* o_b2  = (const float*)d_in[24];
    const float* o_w3  = (const float*)d_in[25];
    const float* o_b3  = (const float*)d_in[26];
    const float* i_w1  = (const float*)d_in[27];
    const float* i_b1  = (const float*)d_in[28];
    const float* i_w2  = (const float*)d_in[29];
    const float* i_b2  = (const float*)d_in[30];
    float* out = (float*)d_out;

    const int B = in_sizes[0] / (T_ * D_);
    dim3 grid(B), block(256);
    hipLaunchKernelGGL(lnn_mf, grid, block, 0, stream,
        X, fg_w1, fg_b1, fg_w2, fg_b2, fwin, fbin, fwrec, swin, sbin, swrec,
        fu_w, fu_b, at_w1, at_b1, at_w2, at_b2, d_w1, d_b1, d_w2, d_b2,
        o_w1, o_b1, o_w2, o_b2, o_w3, o_b3, i_w1, i_b1, i_w2, i_b2, out, B);
}